// Round 1
// baseline (296.344 us; speedup 1.0000x reference)
//
#include <hip/hip_runtime.h>
#include <cstdint>
#include <cstddef>

#define NROWS 4096
#define DIM   1024
#define TWON  8192
#define INV_T 2.0f
// exp(2.0) = exp(sim_rr / T) for the masked diagonal (rows are unit-norm)
#define EXP_DIAG 7.38905609893065f

typedef __bf16 bf16x8 __attribute__((ext_vector_type(8)));
typedef float  floatx4 __attribute__((ext_vector_type(4)));

__device__ __forceinline__ unsigned short f2bf(float f) {
  union { float f; unsigned int u; } a; a.f = f;
  a.u += 0x7FFFu + ((a.u >> 16) & 1u);   // RNE
  return (unsigned short)(a.u >> 16);
}
__device__ __forceinline__ float bf2f(unsigned short h) {
  union { unsigned int u; float f; } a; a.u = ((unsigned int)h) << 16;
  return a.f;
}

__device__ __forceinline__ void gload16(const unsigned short* g, unsigned short* l) {
  __builtin_amdgcn_global_load_lds(
      (const __attribute__((address_space(1))) void*)g,
      (__attribute__((address_space(3))) void*)l,
      16, 0, 0);
}

// ---------------- kernel 1: row L2 normalize -> bf16 reps --------------------
__global__ void normalize_kernel(const float* __restrict__ emb_i,
                                 const float* __restrict__ emb_j,
                                 unsigned short* __restrict__ reps) {
  const int row = blockIdx.x;                 // 0..8191
  const float* src = (row < NROWS) ? emb_i + (size_t)row * DIM
                                   : emb_j + (size_t)(row - NROWS) * DIM;
  const int t = threadIdx.x;                  // 256 threads, 4 floats each
  float4 v = reinterpret_cast<const float4*>(src)[t];
  float ss = v.x * v.x + v.y * v.y + v.z * v.z + v.w * v.w;
#pragma unroll
  for (int o = 32; o; o >>= 1) ss += __shfl_down(ss, o, 64);
  __shared__ float red[4];
  if ((t & 63) == 0) red[t >> 6] = ss;
  __syncthreads();
  float tot = red[0] + red[1] + red[2] + red[3];
  float inv = 1.0f / fmaxf(sqrtf(tot), 1e-12f);
  ushort4 o4;
  o4.x = f2bf(v.x * inv); o4.y = f2bf(v.y * inv);
  o4.z = f2bf(v.z * inv); o4.w = f2bf(v.w * inv);
  reinterpret_cast<ushort4*>(reps + (size_t)row * DIM)[t] = o4;
}

// ------- kernel 2: fused sim-GEMM + exp + row-sum (m97 structure) ------------
// C-tile 128x128, 4 waves in 2x2, each wave 4x4 grid of 16x16x32 MFMAs.
__global__ __launch_bounds__(256) void simsum_kernel(
    const unsigned short* __restrict__ reps, float* __restrict__ denom) {
  __shared__ __align__(16) unsigned short lA[128 * 32];  // 8 KB
  __shared__ __align__(16) unsigned short lB[128 * 32];  // 8 KB
  __shared__ float dl[128];

  const int t    = threadIdx.x;
  const int lane = t & 63;
  const int wave = t >> 6;
  const int wm   = wave >> 1;      // wave row 0..1
  const int wn   = wave & 1;       // wave col 0..1
  const int brow = blockIdx.x >> 6;
  const int bcol = blockIdx.x & 63;

  const unsigned short* gA = reps + (size_t)brow * 128 * DIM;
  const unsigned short* gB = reps + (size_t)bcol * 128 * DIM;
  const int srow = t >> 2;           // staging: 4 threads x 8 elts per 32-col row
  const int scol = (t & 3) << 3;

  floatx4 acc[4][4];
#pragma unroll
  for (int i = 0; i < 4; ++i)
#pragma unroll
    for (int j = 0; j < 4; ++j) acc[i][j] = floatx4{0.f, 0.f, 0.f, 0.f};

  const int mrow = lane & 15;        // fragment row/col select
  const int qk   = (lane >> 4) << 3; // k offset = quad*8

  for (int k0 = 0; k0 < DIM; k0 += 32) {
    __syncthreads();
    gload16(gA + (size_t)srow * DIM + k0 + scol, lA + t * 8);
    gload16(gA + (size_t)(srow + 64) * DIM + k0 + scol, lA + 2048 + t * 8);
    gload16(gB + (size_t)srow * DIM + k0 + scol, lB + t * 8);
    gload16(gB + (size_t)(srow + 64) * DIM + k0 + scol, lB + 2048 + t * 8);
    __syncthreads();   // compiler inserts vmcnt(0) drain here

    bf16x8 af[4], bq[4];
#pragma unroll
    for (int mt = 0; mt < 4; ++mt)
      af[mt] = *reinterpret_cast<const bf16x8*>(&lA[(wm * 64 + mt * 16 + mrow) * 32 + qk]);
#pragma unroll
    for (int nt = 0; nt < 4; ++nt)
      bq[nt] = *reinterpret_cast<const bf16x8*>(&lB[(wn * 64 + nt * 16 + mrow) * 32 + qk]);
#pragma unroll
    for (int mt = 0; mt < 4; ++mt)
#pragma unroll
      for (int nt = 0; nt < 4; ++nt)
        acc[mt][nt] = __builtin_amdgcn_mfma_f32_16x16x32_bf16(af[mt], bq[nt], acc[mt][nt], 0, 0, 0);
  }

  if (t < 128) dl[t] = 0.f;
  __syncthreads();

  // epilogue: e = exp(2*sim); row-sum over the 128 cols this block owns.
  // C/D layout (16x16): col = lane&15, row = (lane>>4)*4 + reg  [m89]
#pragma unroll
  for (int mt = 0; mt < 4; ++mt) {
#pragma unroll
    for (int r = 0; r < 4; ++r) {
      float s = __expf(acc[mt][0][r] * INV_T) + __expf(acc[mt][1][r] * INV_T) +
                __expf(acc[mt][2][r] * INV_T) + __expf(acc[mt][3][r] * INV_T);
      s += __shfl_xor(s, 1, 64);
      s += __shfl_xor(s, 2, 64);
      s += __shfl_xor(s, 4, 64);
      s += __shfl_xor(s, 8, 64);
      if ((lane & 15) == 0)
        atomicAdd(&dl[wm * 64 + mt * 16 + (lane >> 4) * 4 + r], s);
    }
  }
  __syncthreads();
  if (t < 128) atomicAdd(&denom[brow * 128 + t], dl[t]);
}

// -------- kernel 3: positive-pair dots -> -(4*sum dot)/8192 into out ---------
__global__ void pos_kernel(const unsigned short* __restrict__ reps,
                           float* __restrict__ out) {
  const int k = blockIdx.x;   // 0..4095
  const int t = threadIdx.x;
  const unsigned short* a = reps + (size_t)k * DIM;
  const unsigned short* b = reps + (size_t)(k + NROWS) * DIM;
  ushort4 ua = reinterpret_cast<const ushort4*>(a)[t];
  ushort4 ub = reinterpret_cast<const ushort4*>(b)[t];
  float s = bf2f(ua.x) * bf2f(ub.x) + bf2f(ua.y) * bf2f(ub.y) +
            bf2f(ua.z) * bf2f(ub.z) + bf2f(ua.w) * bf2f(ub.w);
#pragma unroll
  for (int o = 32; o; o >>= 1) s += __shfl_down(s, o, 64);
  __shared__ float red[4];
  if ((t & 63) == 0) red[t >> 6] = s;
  __syncthreads();
  if (t == 0) {
    float tot = red[0] + red[1] + red[2] + red[3];
    atomicAdd(out, -tot * (1.0f / 2048.0f));  // = -(4*dot)/8192
  }
}

// -------- kernel 4: sum log(denom - exp_diag) / 8192 into out ----------------
__global__ void logsum_kernel(const float* __restrict__ denom,
                              float* __restrict__ out) {
  const int i = blockIdx.x * 256 + threadIdx.x;
  float v = __logf(denom[i] - EXP_DIAG);
#pragma unroll
  for (int o = 32; o; o >>= 1) v += __shfl_down(v, o, 64);
  __shared__ float red[4];
  if ((threadIdx.x & 63) == 0) red[threadIdx.x >> 6] = v;
  __syncthreads();
  if (threadIdx.x == 0)
    atomicAdd(out, (red[0] + red[1] + red[2] + red[3]) * (1.0f / 8192.0f));
}

extern "C" void kernel_launch(void* const* d_in, const int* in_sizes, int n_in,
                              void* d_out, int out_size, void* d_ws, size_t ws_size,
                              hipStream_t stream) {
  const float* emb_i = (const float*)d_in[0];
  const float* emb_j = (const float*)d_in[1];
  float* out = (float*)d_out;

  unsigned short* reps = (unsigned short*)d_ws;                    // 16.78 MB bf16
  float* denom = (float*)((char*)d_ws + (size_t)TWON * DIM * 2);   // 32 KB

  hipMemsetAsync(out, 0, sizeof(float), stream);
  hipMemsetAsync(denom, 0, TWON * sizeof(float), stream);

  normalize_kernel<<<TWON, 256, 0, stream>>>(emb_i, emb_j, reps);
  simsum_kernel<<<64 * 64, 256, 0, stream>>>(reps, denom);
  pos_kernel<<<NROWS, 256, 0, stream>>>(reps, out);
  logsum_kernel<<<TWON / 256, 256, 0, stream>>>(denom, out);
}

// Round 2
// 218.381 us; speedup vs baseline: 1.3570x; 1.3570x over previous
//
#include <hip/hip_runtime.h>
#include <cstdint>
#include <cstddef>

#define NROWS 4096
#define DIM   1024
#define TWON  8192
#define INV_T 2.0f
// exp(2.0) = exp(sim_rr / T) for the masked diagonal (rows are unit-norm)
#define EXP_DIAG 7.38905609893065f

typedef __bf16 bf16x8 __attribute__((ext_vector_type(8)));
typedef float  floatx4 __attribute__((ext_vector_type(4)));

__device__ __forceinline__ unsigned short f2bf(float f) {
  union { float f; unsigned int u; } a; a.f = f;
  a.u += 0x7FFFu + ((a.u >> 16) & 1u);   // RNE
  return (unsigned short)(a.u >> 16);
}

__device__ __forceinline__ void gload16(const unsigned short* g, unsigned short* l) {
  __builtin_amdgcn_global_load_lds(
      (const __attribute__((address_space(1))) void*)g,
      (__attribute__((address_space(3))) void*)l,
      16, 0, 0);
}

// -------- kernel 1: normalize rows k and k+N, fp32 positive dot, zero denom --
__global__ __launch_bounds__(256) void normpos_kernel(
    const float* __restrict__ emb_i, const float* __restrict__ emb_j,
    unsigned short* __restrict__ reps, float* __restrict__ denom,
    float* __restrict__ out) {
  const int k = blockIdx.x;                   // 0..4095 (pair index)
  const int t = threadIdx.x;                  // 256 threads, 4 floats per row
  if (k < 32) denom[k * 256 + t] = 0.f;       // stream-ordered before simsum

  float4 vi = reinterpret_cast<const float4*>(emb_i + (size_t)k * DIM)[t];
  float4 vj = reinterpret_cast<const float4*>(emb_j + (size_t)k * DIM)[t];
  float ssi = vi.x * vi.x + vi.y * vi.y + vi.z * vi.z + vi.w * vi.w;
  float ssj = vj.x * vj.x + vj.y * vj.y + vj.z * vj.z + vj.w * vj.w;
  float dot = vi.x * vj.x + vi.y * vj.y + vi.z * vj.z + vi.w * vj.w;
#pragma unroll
  for (int o = 32; o; o >>= 1) {
    ssi += __shfl_down(ssi, o, 64);
    ssj += __shfl_down(ssj, o, 64);
    dot += __shfl_down(dot, o, 64);
  }
  __shared__ float red[3][4];
  if ((t & 63) == 0) {
    red[0][t >> 6] = ssi; red[1][t >> 6] = ssj; red[2][t >> 6] = dot;
  }
  __syncthreads();
  float ti = red[0][0] + red[0][1] + red[0][2] + red[0][3];
  float tj = red[1][0] + red[1][1] + red[1][2] + red[1][3];
  float invi = 1.0f / fmaxf(sqrtf(ti), 1e-12f);
  float invj = 1.0f / fmaxf(sqrtf(tj), 1e-12f);
  ushort4 oi, oj;
  oi.x = f2bf(vi.x * invi); oi.y = f2bf(vi.y * invi);
  oi.z = f2bf(vi.z * invi); oi.w = f2bf(vi.w * invi);
  oj.x = f2bf(vj.x * invj); oj.y = f2bf(vj.y * invj);
  oj.z = f2bf(vj.z * invj); oj.w = f2bf(vj.w * invj);
  reinterpret_cast<ushort4*>(reps + (size_t)k * DIM)[t] = oi;
  reinterpret_cast<ushort4*>(reps + (size_t)(k + NROWS) * DIM)[t] = oj;
  if (t == 0) {
    float td = red[2][0] + red[2][1] + red[2][2] + red[2][3];
    // positives term: -(1/T)*2*sum(dot)/8192 = -dot/2048 per pair
    atomicAdd(out, -td * invi * invj * (1.0f / 2048.0f));
  }
}

// ------- kernel 2: fused sim-GEMM + exp + row/col sums, upper triangle -------
// C-tile 128x128, 4 waves in 2x2, each wave 4x4 grid of 16x16x32 MFMAs.
// Symmetry: off-diag tile (brow<bcol) contributes row-sums to brow rows and
// col-sums (== mirrored row-sums) to bcol rows.
__global__ __launch_bounds__(256) void simsum_kernel(
    const unsigned short* __restrict__ reps, float* __restrict__ denom) {
  __shared__ __align__(16) unsigned short lA[128 * 32];  // 8 KB
  __shared__ __align__(16) unsigned short lB[128 * 32];  // 8 KB
  __shared__ float dl[128];   // row-side partial sums
  __shared__ float cl[128];   // col-side partial sums

  const int t    = threadIdx.x;
  const int lane = t & 63;
  const int wave = t >> 6;
  const int wm   = wave >> 1;      // wave row 0..1
  const int wn   = wave & 1;       // wave col 0..1

  // triangular unranking: f(b) = b*(129-b)/2 tiles before block-row b
  const int idx = blockIdx.x;      // 0..2079
  int brow = (int)(64.5f - sqrtf(64.5f * 64.5f - 2.0f * (float)idx));
  if (brow > 63) brow = 63;
  if (brow < 0) brow = 0;
  while ((brow + 1) * (129 - (brow + 1)) / 2 <= idx) ++brow;
  while (brow * (129 - brow) / 2 > idx) --brow;
  const int bcol = brow + (idx - brow * (129 - brow) / 2);
  const bool offdiag = (brow != bcol);

  const unsigned short* gA = reps + (size_t)brow * 128 * DIM;
  const unsigned short* gB = reps + (size_t)bcol * 128 * DIM;
  const int srow = t >> 2;           // staging: 4 threads x 8 elts per 32-col row
  const int scol = (t & 3) << 3;

  floatx4 acc[4][4];
#pragma unroll
  for (int i = 0; i < 4; ++i)
#pragma unroll
    for (int j = 0; j < 4; ++j) acc[i][j] = floatx4{0.f, 0.f, 0.f, 0.f};

  const int mrow = lane & 15;        // fragment row/col select
  const int qk   = (lane >> 4) << 3; // k offset = quad*8

  for (int k0 = 0; k0 < DIM; k0 += 32) {
    __syncthreads();
    gload16(gA + (size_t)srow * DIM + k0 + scol, lA + t * 8);
    gload16(gA + (size_t)(srow + 64) * DIM + k0 + scol, lA + 2048 + t * 8);
    gload16(gB + (size_t)srow * DIM + k0 + scol, lB + t * 8);
    gload16(gB + (size_t)(srow + 64) * DIM + k0 + scol, lB + 2048 + t * 8);
    __syncthreads();   // compiler inserts vmcnt(0) drain here

    bf16x8 af[4], bq[4];
#pragma unroll
    for (int mt = 0; mt < 4; ++mt)
      af[mt] = *reinterpret_cast<const bf16x8*>(&lA[(wm * 64 + mt * 16 + mrow) * 32 + qk]);
#pragma unroll
    for (int nt = 0; nt < 4; ++nt)
      bq[nt] = *reinterpret_cast<const bf16x8*>(&lB[(wn * 64 + nt * 16 + mrow) * 32 + qk]);
#pragma unroll
    for (int mt = 0; mt < 4; ++mt)
#pragma unroll
      for (int nt = 0; nt < 4; ++nt)
        acc[mt][nt] = __builtin_amdgcn_mfma_f32_16x16x32_bf16(af[mt], bq[nt], acc[mt][nt], 0, 0, 0);
  }

  if (t < 128) dl[t] = 0.f; else cl[t - 128] = 0.f;
  __syncthreads();

  // exp in-place: acc now holds e = exp(sim/T)
#pragma unroll
  for (int mt = 0; mt < 4; ++mt)
#pragma unroll
    for (int nt = 0; nt < 4; ++nt)
#pragma unroll
      for (int r = 0; r < 4; ++r)
        acc[mt][nt][r] = __expf(acc[mt][nt][r] * INV_T);

  // row-sums: C/D layout (16x16): col = lane&15, row = (lane>>4)*4 + reg [m89]
#pragma unroll
  for (int mt = 0; mt < 4; ++mt) {
#pragma unroll
    for (int r = 0; r < 4; ++r) {
      float s = acc[mt][0][r] + acc[mt][1][r] + acc[mt][2][r] + acc[mt][3][r];
      s += __shfl_xor(s, 1, 64);
      s += __shfl_xor(s, 2, 64);
      s += __shfl_xor(s, 4, 64);
      s += __shfl_xor(s, 8, 64);
      if ((lane & 15) == 0)
        atomicAdd(&dl[wm * 64 + mt * 16 + (lane >> 4) * 4 + r], s);
    }
  }

  // col-sums (mirror rows), off-diag tiles only
  if (offdiag) {
#pragma unroll
    for (int nt = 0; nt < 4; ++nt) {
      float c = 0.f;
#pragma unroll
      for (int mt = 0; mt < 4; ++mt)
#pragma unroll
        for (int r = 0; r < 4; ++r) c += acc[mt][nt][r];
      c += __shfl_xor(c, 16, 64);
      c += __shfl_xor(c, 32, 64);
      if ((lane >> 4) == 0)
        atomicAdd(&cl[wn * 64 + nt * 16 + (lane & 15)], c);
    }
  }
  __syncthreads();
  if (t < 128) {
    atomicAdd(&denom[brow * 128 + t], dl[t]);
    if (offdiag) atomicAdd(&denom[bcol * 128 + t], cl[t]);
  }
}

// -------- kernel 3: sum log(denom - exp_diag) / 8192 into out ----------------
__global__ void logsum_kernel(const float* __restrict__ denom,
                              float* __restrict__ out) {
  const int i = blockIdx.x * 256 + threadIdx.x;
  float v = __logf(denom[i] - EXP_DIAG);
#pragma unroll
  for (int o = 32; o; o >>= 1) v += __shfl_down(v, o, 64);
  __shared__ float red[4];
  if ((threadIdx.x & 63) == 0) red[threadIdx.x >> 6] = v;
  __syncthreads();
  if (threadIdx.x == 0)
    atomicAdd(out, (red[0] + red[1] + red[2] + red[3]) * (1.0f / 8192.0f));
}

extern "C" void kernel_launch(void* const* d_in, const int* in_sizes, int n_in,
                              void* d_out, int out_size, void* d_ws, size_t ws_size,
                              hipStream_t stream) {
  const float* emb_i = (const float*)d_in[0];
  const float* emb_j = (const float*)d_in[1];
  float* out = (float*)d_out;

  unsigned short* reps = (unsigned short*)d_ws;                    // 16.78 MB bf16
  float* denom = (float*)((char*)d_ws + (size_t)TWON * DIM * 2);   // 32 KB

  hipMemsetAsync(out, 0, sizeof(float), stream);

  normpos_kernel<<<NROWS, 256, 0, stream>>>(emb_i, emb_j, reps, denom, out);
  simsum_kernel<<<64 * 65 / 2, 256, 0, stream>>>(reps, denom);
  logsum_kernel<<<TWON / 256, 256, 0, stream>>>(denom, out);
}

// Round 3
// 180.306 us; speedup vs baseline: 1.6436x; 1.2112x over previous
//
#include <hip/hip_runtime.h>
#include <cstdint>
#include <cstddef>

#define NROWS 4096
#define DIM   1024
#define TWON  8192
#define INV_T 2.0f
// exp(2.0) = exp(sim_rr / T) for the masked diagonal (rows are unit-norm)
#define EXP_DIAG 7.38905609893065f
#define BK 64

typedef __bf16 bf16x8 __attribute__((ext_vector_type(8)));
typedef float  floatx4 __attribute__((ext_vector_type(4)));

__device__ __forceinline__ unsigned short f2bf(float f) {
  union { float f; unsigned int u; } a; a.f = f;
  a.u += 0x7FFFu + ((a.u >> 16) & 1u);   // RNE
  return (unsigned short)(a.u >> 16);
}

__device__ __forceinline__ void gload16(const unsigned short* g, unsigned short* l) {
  __builtin_amdgcn_global_load_lds(
      (const __attribute__((address_space(1))) void*)g,
      (__attribute__((address_space(3))) void*)l,
      16, 0, 0);
}

// -- kernel 1: normalize rows k and k+N, fp32 positive dot -> pos[], zero denom
__global__ __launch_bounds__(256) void normpos_kernel(
    const float* __restrict__ emb_i, const float* __restrict__ emb_j,
    unsigned short* __restrict__ reps, float* __restrict__ denom,
    float* __restrict__ pos) {
  const int k = blockIdx.x;                   // 0..4095 (pair index)
  const int t = threadIdx.x;                  // 256 threads, 4 floats per row
  if (k < 32) denom[k * 256 + t] = 0.f;       // stream-ordered before simsum

  float4 vi = reinterpret_cast<const float4*>(emb_i + (size_t)k * DIM)[t];
  float4 vj = reinterpret_cast<const float4*>(emb_j + (size_t)k * DIM)[t];
  float ssi = vi.x * vi.x + vi.y * vi.y + vi.z * vi.z + vi.w * vi.w;
  float ssj = vj.x * vj.x + vj.y * vj.y + vj.z * vj.z + vj.w * vj.w;
  float dot = vi.x * vj.x + vi.y * vj.y + vi.z * vj.z + vi.w * vj.w;
#pragma unroll
  for (int o = 32; o; o >>= 1) {
    ssi += __shfl_down(ssi, o, 64);
    ssj += __shfl_down(ssj, o, 64);
    dot += __shfl_down(dot, o, 64);
  }
  __shared__ float red[3][4];
  if ((t & 63) == 0) {
    red[0][t >> 6] = ssi; red[1][t >> 6] = ssj; red[2][t >> 6] = dot;
  }
  __syncthreads();
  float ti = red[0][0] + red[0][1] + red[0][2] + red[0][3];
  float tj = red[1][0] + red[1][1] + red[1][2] + red[1][3];
  float invi = 1.0f / fmaxf(sqrtf(ti), 1e-12f);
  float invj = 1.0f / fmaxf(sqrtf(tj), 1e-12f);
  ushort4 oi, oj;
  oi.x = f2bf(vi.x * invi); oi.y = f2bf(vi.y * invi);
  oi.z = f2bf(vi.z * invi); oi.w = f2bf(vi.w * invi);
  oj.x = f2bf(vj.x * invj); oj.y = f2bf(vj.y * invj);
  oj.z = f2bf(vj.z * invj); oj.w = f2bf(vj.w * invj);
  reinterpret_cast<ushort4*>(reps + (size_t)k * DIM)[t] = oi;
  reinterpret_cast<ushort4*>(reps + (size_t)(k + NROWS) * DIM)[t] = oj;
  if (t == 0) {
    float td = red[2][0] + red[2][1] + red[2][2] + red[2][3];
    pos[k] = td * invi * invj;   // cosine of the positive pair, fp32
  }
}

// ------- kernel 2: fused sim-GEMM + exp + row/col sums, upper triangle -------
// C-tile 128x128, 4 waves 2x2, each wave 4x4 grid of 16x16x32 MFMAs, BK=64.
// LDS staging is XOR-swizzled by row&7 (chunk granularity 16B) so fragment
// ds_read_b128s spread over all 32 banks (global_load_lds forbids padding).
__global__ __launch_bounds__(256) void simsum_kernel(
    const unsigned short* __restrict__ reps, float* __restrict__ denom) {
  __shared__ __align__(16) unsigned short lA[128 * BK];  // 16 KB
  __shared__ __align__(16) unsigned short lB[128 * BK];  // 16 KB
  __shared__ float dl[128];   // row-side partial sums
  __shared__ float cl[128];   // col-side partial sums

  const int t    = threadIdx.x;
  const int lane = t & 63;
  const int wave = t >> 6;
  const int wm   = wave >> 1;      // wave row 0..1
  const int wn   = wave & 1;       // wave col 0..1

  // triangular unranking: f(b) = b*(129-b)/2 tiles before block-row b
  const int idx = blockIdx.x;      // 0..2079
  int brow = (int)(64.5f - sqrtf(64.5f * 64.5f - 2.0f * (float)idx));
  if (brow > 63) brow = 63;
  if (brow < 0) brow = 0;
  while ((brow + 1) * (129 - (brow + 1)) / 2 <= idx) ++brow;
  while (brow * (129 - brow) / 2 > idx) --brow;
  const int bcol = brow + (idx - brow * (129 - brow) / 2);
  const bool offdiag = (brow != bcol);

  const unsigned short* gA = reps + (size_t)brow * 128 * DIM;
  const unsigned short* gB = reps + (size_t)bcol * 128 * DIM;

  // staging: thread t serves row srow (per 32-row call), swizzled 16B chunk
  const int srow  = t >> 3;                        // 0..31
  const int scswz = ((t & 7) ^ (srow & 7)) << 3;   // swizzled short offset
  const size_t gOff = (size_t)srow * DIM + scswz;

  floatx4 acc[4][4];
#pragma unroll
  for (int i = 0; i < 4; ++i)
#pragma unroll
    for (int j = 0; j < 4; ++j) acc[i][j] = floatx4{0.f, 0.f, 0.f, 0.f};

  const int mrow = lane & 15;        // fragment row select
  const int hi   = lane >> 4;        // k quad 0..3
  const int kkey = mrow & 7;         // swizzle key (wm*64, mt*16 are 0 mod 8)

  for (int k0 = 0; k0 < DIM; k0 += BK) {
    __syncthreads();
#pragma unroll
    for (int q = 0; q < 4; ++q) {
      gload16(gA + gOff + (size_t)q * 32 * DIM + k0, lA + q * 2048 + t * 8);
      gload16(gB + gOff + (size_t)q * 32 * DIM + k0, lB + q * 2048 + t * 8);
    }
    __syncthreads();   // compiler inserts vmcnt(0) drain here

#pragma unroll
    for (int ks = 0; ks < BK; ks += 32) {
      bf16x8 af[4], bq[4];
#pragma unroll
      for (int mt = 0; mt < 4; ++mt)
        af[mt] = *reinterpret_cast<const bf16x8*>(
            &lA[(wm * 64 + mt * 16 + mrow) * BK + ((((ks >> 3) + hi) ^ kkey) << 3)]);
#pragma unroll
      for (int nt = 0; nt < 4; ++nt)
        bq[nt] = *reinterpret_cast<const bf16x8*>(
            &lB[(wn * 64 + nt * 16 + mrow) * BK + ((((ks >> 3) + hi) ^ kkey) << 3)]);
#pragma unroll
      for (int mt = 0; mt < 4; ++mt)
#pragma unroll
        for (int nt = 0; nt < 4; ++nt)
          acc[mt][nt] = __builtin_amdgcn_mfma_f32_16x16x32_bf16(af[mt], bq[nt], acc[mt][nt], 0, 0, 0);
    }
  }

  if (t < 128) dl[t] = 0.f; else cl[t - 128] = 0.f;
  __syncthreads();

  // exp in-place: acc now holds e = exp(sim/T)
#pragma unroll
  for (int mt = 0; mt < 4; ++mt)
#pragma unroll
    for (int nt = 0; nt < 4; ++nt)
#pragma unroll
      for (int r = 0; r < 4; ++r)
        acc[mt][nt][r] = __expf(acc[mt][nt][r] * INV_T);

  // row-sums: C/D layout (16x16): col = lane&15, row = (lane>>4)*4 + reg [m89]
#pragma unroll
  for (int mt = 0; mt < 4; ++mt) {
#pragma unroll
    for (int r = 0; r < 4; ++r) {
      float s = acc[mt][0][r] + acc[mt][1][r] + acc[mt][2][r] + acc[mt][3][r];
      s += __shfl_xor(s, 1, 64);
      s += __shfl_xor(s, 2, 64);
      s += __shfl_xor(s, 4, 64);
      s += __shfl_xor(s, 8, 64);
      if ((lane & 15) == 0)
        atomicAdd(&dl[wm * 64 + mt * 16 + (lane >> 4) * 4 + r], s);
    }
  }

  // col-sums (mirror rows), off-diag tiles only
  if (offdiag) {
#pragma unroll
    for (int nt = 0; nt < 4; ++nt) {
      float c = 0.f;
#pragma unroll
      for (int mt = 0; mt < 4; ++mt)
#pragma unroll
        for (int r = 0; r < 4; ++r) c += acc[mt][nt][r];
      c += __shfl_xor(c, 16, 64);
      c += __shfl_xor(c, 32, 64);
      if ((lane >> 4) == 0)
        atomicAdd(&cl[wn * 64 + nt * 16 + (lane & 15)], c);
    }
  }
  __syncthreads();
  if (t < 128) {
    atomicAdd(&denom[brow * 128 + t], dl[t]);
    if (offdiag) atomicAdd(&denom[bcol * 128 + t], cl[t]);
  }
}

// -- kernel 3 (single block): out = (sum log(denom - e^2) - 4*sum pos) / 8192 -
__global__ __launch_bounds__(256) void final_kernel(
    const float* __restrict__ denom, const float* __restrict__ pos,
    float* __restrict__ out) {
  const int t = threadIdx.x;
  float v = 0.f;
#pragma unroll
  for (int i = 0; i < TWON / 256; ++i)
    v += __logf(denom[i * 256 + t] - EXP_DIAG);
  float p = 0.f;
#pragma unroll
  for (int i = 0; i < NROWS / 256; ++i)
    p += pos[i * 256 + t];
  v -= 4.0f * p;
#pragma unroll
  for (int o = 32; o; o >>= 1) v += __shfl_down(v, o, 64);
  __shared__ float red[4];
  if ((t & 63) == 0) red[t >> 6] = v;
  __syncthreads();
  if (t == 0)
    out[0] = (red[0] + red[1] + red[2] + red[3]) * (1.0f / 8192.0f);
}

extern "C" void kernel_launch(void* const* d_in, const int* in_sizes, int n_in,
                              void* d_out, int out_size, void* d_ws, size_t ws_size,
                              hipStream_t stream) {
  const float* emb_i = (const float*)d_in[0];
  const float* emb_j = (const float*)d_in[1];
  float* out = (float*)d_out;

  unsigned short* reps = (unsigned short*)d_ws;                    // 16.78 MB bf16
  float* denom = (float*)((char*)d_ws + (size_t)TWON * DIM * 2);   // 32 KB
  float* pos   = denom + TWON;                                     // 16 KB

  normpos_kernel<<<NROWS, 256, 0, stream>>>(emb_i, emb_j, reps, denom, pos);
  simsum_kernel<<<64 * 65 / 2, 256, 0, stream>>>(reps, denom);
  final_kernel<<<1, 256, 0, stream>>>(denom, pos, out);
}